// Round 1
// baseline (143.954 us; speedup 1.0000x reference)
//
#include <hip/hip_runtime.h>
#include <hip/hip_bf16.h>

// ScaledDotProductAttentionEnriched: BH=64, S=1024, DK=64, FG=FL=32.
// Flash attention with transposed scores (S^T = K_enr * Q_enr^T) via
// mfma_f32_32x32x16_bf16. Mask bias + 1/sqrt(dk)*log2(e) scale baked into an
// extra enriched-K chunk (D 128 -> 144). P converted C-layout -> B-operand
// layout in-register (lane^32 half exchange). Output transposed via LDS for
// coalesced fp32 stores.

#define BHn 64
#define Sn  1024
#define DKn 64
#define BQ  128
#define BK  128
#define KSTR 152   // k-tile row stride (bf16): 144 cols + 8 pad -> dword stride 76 (=12 mod 32)
#define VSTR 136   // vt row stride (bf16): 128 + 8 pad -> dword stride 68 (=4 mod 32)
#define OSTR 68    // o_lds row stride (f32)

typedef __attribute__((ext_vector_type(8)))  __bf16 bf16x8;
typedef __attribute__((ext_vector_type(16))) float  f32x16;
typedef __attribute__((ext_vector_type(4)))  unsigned int u32x4;
typedef __attribute__((ext_vector_type(2)))  unsigned int u32x2;

__device__ __forceinline__ unsigned f2bf1(float a){
    union { float f; unsigned u; } c; c.f = a;
    return (c.u + 0x7fffu + ((c.u >> 16) & 1u)) >> 16;   // RNE f32->bf16
}
__device__ __forceinline__ unsigned f2bf2(float a, float b){
    return f2bf1(a) | (f2bf1(b) << 16);
}
__device__ __forceinline__ void wr4(unsigned short* p, float4 f){
    u32x2 w; w.x = f2bf2(f.x, f.y); w.y = f2bf2(f.z, f.w);
    *(u32x2*)p = w;                                       // ds_write_b64
}

__global__ __launch_bounds__(256, 2)
void attn_enr_kernel(const float* __restrict__ Q, const float* __restrict__ K,
                     const float* __restrict__ V, const float* __restrict__ LF,
                     const float* __restrict__ GF, const int* __restrict__ M,
                     float* __restrict__ O)
{
    __shared__ __align__(16) unsigned char smem[BK*KSTR*2 + DKn*VSTR*2]; // 56320 B
    unsigned short* kt_s = (unsigned short*)smem;
    unsigned short* vt_s = (unsigned short*)(smem + BK*KSTR*2);

    const int tid  = threadIdx.x;
    const int wave = tid >> 6;
    const int lane = tid & 63;
    const int l31  = lane & 31;
    const int h    = lane >> 5;

    // bh in low bits: the 8 q-blocks of one bh land on one XCD (L2 locality)
    const int bh = blockIdx.x & 63;
    const int qb = blockIdx.x >> 6;

    const float SCL = 0.18033688011112042f;  // 0.125 * log2(e)

    // ---- Q fragments, B-operand layout: B[d=16*dc+8h+j][q=l31], kept in regs ----
    const int qrow = qb*BQ + wave*32 + l31;
    u32x4 qf[9];
    #pragma unroll
    for (int dc = 0; dc < 8; dc++){
        const int cb = dc*16 + 8*h;   // 8-float chunk never straddles a source
        const float* src;
        if (cb < 64)      src = Q  + ((size_t)bh*Sn + qrow)*64 + cb;
        else if (cb < 96) src = GF + ((size_t)bh*Sn + qrow)*32 + (cb - 64);
        else              src = LF + ((size_t)bh*Sn + qrow)*32 + (cb - 96);
        float4 f0 = *(const float4*)src;
        float4 f1 = *(const float4*)(src + 4);
        qf[dc][0] = f2bf2(f0.x*SCL, f0.y*SCL);
        qf[dc][1] = f2bf2(f0.z*SCL, f0.w*SCL);
        qf[dc][2] = f2bf2(f1.x*SCL, f1.y*SCL);
        qf[dc][3] = f2bf2(f1.z*SCL, f1.w*SCL);
    }
    qf[8][0] = h ? 0u : 0x00003f80u;  // bf16(1.0) at col 128; rest zeros
    qf[8][1] = 0u; qf[8][2] = 0u; qf[8][3] = 0u;

    f32x16 oacc[2];
    #pragma unroll
    for (int dt=0; dt<2; dt++)
        #pragma unroll
        for (int r=0; r<16; r++) oacc[dt][r] = 0.f;
    float mrun = -3.0e38f, lrun = 0.f;

    for (int kb = 0; kb < Sn; kb += BK){
        __syncthreads();
        // ---- stage K enriched tile [128][144] as bf16 ----
        #pragma unroll
        for (int i=0;i<8;i++){
            int idx = tid + 256*i, row = idx>>4, c = idx&15;
            float4 f = *(const float4*)(K + ((size_t)bh*Sn + kb + row)*64 + c*4);
            wr4(kt_s + row*KSTR + c*4, f);
        }
        #pragma unroll
        for (int i=0;i<4;i++){
            int idx = tid + 256*i, row = idx>>3, c = idx&7;
            float4 f = *(const float4*)(GF + ((size_t)bh*Sn + kb + row)*32 + c*4);
            wr4(kt_s + row*KSTR + 64 + c*4, f);
        }
        #pragma unroll
        for (int i=0;i<4;i++){
            int idx = tid + 256*i, row = idx>>3, c = idx&7;
            float4 f = *(const float4*)(LF + ((size_t)bh*Sn + kb + row)*32 + c*4);
            wr4(kt_s + row*KSTR + 96 + c*4, f);
        }
        if (tid < BK){
            int mv = M[(size_t)bh*Sn + kb + tid];
            u32x4 w; w[0] = (mv == 1) ? 0x0000ceacu : 0u;  // bf16(-1e9*log2e)
            w[1] = 0u; w[2] = 0u; w[3] = 0u;
            *(u32x4*)(kt_s + tid*KSTR + 128) = w;
            u32x4 z; z[0]=0u; z[1]=0u; z[2]=0u; z[3]=0u;
            *(u32x4*)(kt_s + tid*KSTR + 136) = z;
        }
        // ---- stage V transposed: vt[d][k] ----
        {
            int d = tid & 63, kg = tid >> 6;
            #pragma unroll
            for (int j=0;j<8;j++){
                int k0 = kg*32 + j*4;
                const float* vp = V + ((size_t)bh*Sn + kb + k0)*64 + d;
                u32x2 w; w.x = f2bf2(vp[0], vp[64]); w.y = f2bf2(vp[128], vp[192]);
                *(u32x2*)(vt_s + d*VSTR + k0) = w;
            }
        }
        __syncthreads();

        // ---- S^T = K_enr * Q_enr^T : rows = key pos, cols = q pos ----
        f32x16 sc[4];
        #pragma unroll
        for (int kt=0; kt<4; kt++){
            f32x16 acc;
            #pragma unroll
            for (int r=0;r<16;r++) acc[r] = 0.f;
            #pragma unroll
            for (int dc=0; dc<9; dc++){
                u32x4 ar = *(const u32x4*)(kt_s + (kt*32 + l31)*KSTR + dc*16 + 8*h);
                acc = __builtin_amdgcn_mfma_f32_32x32x16_bf16(
                        __builtin_bit_cast(bf16x8, ar),
                        __builtin_bit_cast(bf16x8, qf[dc]), acc, 0, 0, 0);
            }
            sc[kt] = acc;
        }

        // ---- online softmax per q (= per lane&31, halves hold disjoint k-rows) ----
        float mx = -3.0e38f;
        #pragma unroll
        for (int kt=0;kt<4;kt++)
            #pragma unroll
            for (int r=0;r<16;r++) mx = fmaxf(mx, sc[kt][r]);
        mx = fmaxf(mx, __shfl_xor(mx, 32, 64));
        float mnew  = fmaxf(mrun, mx);
        float alpha = __builtin_amdgcn_exp2f(mrun - mnew);
        float rs = 0.f;
        #pragma unroll
        for (int kt=0;kt<4;kt++)
            #pragma unroll
            for (int r=0;r<16;r++){
                float p = __builtin_amdgcn_exp2f(sc[kt][r] - mnew);
                sc[kt][r] = p; rs += p;
            }
        lrun = lrun*alpha + rs;   // per-half partial sum; combined at epilogue
        mrun = mnew;
        #pragma unroll
        for (int dt=0;dt<2;dt++)
            #pragma unroll
            for (int r=0;r<16;r++) oacc[dt][r] *= alpha;

        // ---- PV: O^T += V^T * P ; P C-layout -> B-frag via lane^32 exchange ----
        #pragma unroll
        for (int kt=0;kt<4;kt++){
            unsigned pk[8], px[8];
            #pragma unroll
            for (int i=0;i<8;i++) pk[i] = f2bf2(sc[kt][2*i], sc[kt][2*i+1]);
            #pragma unroll
            for (int i=0;i<8;i++) px[i] = (unsigned)__shfl_xor((int)pk[i], 32, 64);
            u32x4 b0, b1;
            b0[0] = h ? px[2] : pk[0];  b0[1] = h ? px[3] : pk[1];
            b0[2] = h ? pk[2] : px[0];  b0[3] = h ? pk[3] : px[1];
            b1[0] = h ? px[6] : pk[4];  b1[1] = h ? px[7] : pk[5];
            b1[2] = h ? pk[6] : px[4];  b1[3] = h ? pk[7] : px[5];
            #pragma unroll
            for (int dt=0;dt<2;dt++){
                u32x4 va0 = *(const u32x4*)(vt_s + (dt*32 + l31)*VSTR + kt*32 + 8*h);
                u32x4 va1 = *(const u32x4*)(vt_s + (dt*32 + l31)*VSTR + kt*32 + 16 + 8*h);
                oacc[dt] = __builtin_amdgcn_mfma_f32_32x32x16_bf16(
                        __builtin_bit_cast(bf16x8, va0),
                        __builtin_bit_cast(bf16x8, b0), oacc[dt], 0, 0, 0);
                oacc[dt] = __builtin_amdgcn_mfma_f32_32x32x16_bf16(
                        __builtin_bit_cast(bf16x8, va1),
                        __builtin_bit_cast(bf16x8, b1), oacc[dt], 0, 0, 0);
            }
        }
    }

    // ---- epilogue: normalize, transpose via LDS, coalesced f32 stores ----
    __syncthreads();
    float lt  = lrun + __shfl_xor(lrun, 32, 64);
    float inv = 1.0f / lt;
    float* olds = (float*)smem;   // [128][OSTR], 34816 B, overlays kt_s
    #pragma unroll
    for (int dt=0;dt<2;dt++)
        #pragma unroll
        for (int rg=0;rg<4;rg++){
            float4 w;
            w.x = oacc[dt][rg*4+0]*inv;
            w.y = oacc[dt][rg*4+1]*inv;
            w.z = oacc[dt][rg*4+2]*inv;
            w.w = oacc[dt][rg*4+3]*inv;
            int d = dt*32 + rg*8 + 4*h;
            *(float4*)(olds + (wave*32 + l31)*OSTR + d) = w;
        }
    __syncthreads();
    #pragma unroll
    for (int i=0;i<8;i++){
        int idx = tid + 256*i, r = idx>>4, c = idx&15;
        float4 w = *(const float4*)(olds + r*OSTR + c*4);
        *(float4*)(O + ((size_t)bh*Sn + qb*BQ + r)*64 + c*4) = w;
    }
}

extern "C" void kernel_launch(void* const* d_in, const int* in_sizes, int n_in,
                              void* d_out, int out_size, void* d_ws, size_t ws_size,
                              hipStream_t stream) {
    const float* Q  = (const float*)d_in[0];
    const float* K  = (const float*)d_in[1];
    const float* V  = (const float*)d_in[2];
    const float* LF = (const float*)d_in[3];   // local_f
    const float* GF = (const float*)d_in[4];   // global_f
    const int*   M  = (const int*)d_in[5];
    float* O = (float*)d_out;
    attn_enr_kernel<<<dim3(BHn * (Sn/BQ)), dim3(256), 0, stream>>>(Q, K, V, LF, GF, M, O);
}